// Round 2
// baseline (240.648 us; speedup 1.0000x reference)
//
#include <hip/hip_runtime.h>

// YOLO loss: B=16384, 7x7 grid, pred=30 ch (f32), targ=25 ch (f32), scalar out.
// Memory-bound: 176.7 MB read -> ~28 us HBM roofline (6.3 TB/s achievable).
// Strategy: coalesced float4 global->LDS staging (transpose), then 1 thread/cell.
// LDS pred rows padded to 31 floats (odd stride -> conflict-free reads, m136);
// targ stride 25 already odd. 128 cells/block = 28 KB LDS -> 5 blocks/CU.

#define TPB 128            // threads per block == cells per block
#define PRED_CH 30
#define TARG_CH 25
#define PRED_PAD 31        // padded LDS row stride for pred

__global__ __launch_bounds__(TPB) void yolo_loss_kernel(
    const float* __restrict__ pred,
    const float* __restrict__ targ,
    float* __restrict__ out)
{
    __shared__ float sp[TPB * PRED_PAD];  // 15872 B
    __shared__ float st[TPB * TARG_CH];   // 12800 B

    const int tid   = threadIdx.x;
    const int cell0 = blockIdx.x * TPB;

    // ---- stage predictions: 128*30 = 3840 floats = 960 float4, coalesced ----
    {
        const float4* gp = reinterpret_cast<const float4*>(pred + (size_t)cell0 * PRED_CH);
        for (int i = tid; i < (TPB * PRED_CH) / 4; i += TPB) {
            float4 v = gp[i];
            int f = i * 4;
            #pragma unroll
            for (int j = 0; j < 4; ++j) {
                int ff = f + j;
                int c  = ff / PRED_CH;          // magic-mul division by 30
                int ch = ff - c * PRED_CH;
                sp[c * PRED_PAD + ch] = (&v.x)[j];
            }
        }
    }
    // ---- stage targets: 128*25 = 3200 floats = 800 float4, coalesced ----
    {
        const float4* gt = reinterpret_cast<const float4*>(targ + (size_t)cell0 * TARG_CH);
        float4* st4 = reinterpret_cast<float4*>(st);
        for (int i = tid; i < (TPB * TARG_CH) / 4; i += TPB)
            st4[i] = gt[i];                      // linear layout, stride-25 rows
    }
    __syncthreads();

    // ---- per-cell compute (1 thread = 1 cell), branch-free ----
    const float* pv = sp + tid * PRED_PAD;
    const float* tv = st + tid * TARG_CH;

    float c1 = pv[4], c2 = pv[9], cc = tv[4];
    bool present = (cc == 1.0f);
    bool resp1   = (c1 > c2);

    float d1 = c1 - cc, d2 = c2 - cc;
    float obj_present = resp1 ? d1 * d1 : d2 * d2;
    float obj_absent  = 0.5f * (c1 * c1 + c2 * c2);
    float obj = present ? obj_present : obj_absent;

    float cls = 0.0f;
    #pragma unroll
    for (int k = 0; k < 20; ++k) {
        float d = pv[10 + k] - tv[5 + k];
        cls += d * d;
    }

    float pc0 = resp1 ? pv[0] : pv[5];
    float pc1 = resp1 ? pv[1] : pv[6];
    float ph0 = resp1 ? pv[2] : pv[7];
    float ph1 = resp1 ? pv[3] : pv[8];
    float b0 = pc0 - tv[0];
    float b1 = pc1 - tv[1];
    float s0 = sqrtf(ph0) - sqrtf(tv[2]);
    float s1 = sqrtf(ph1) - sqrtf(tv[3]);
    float box = b0 * b0 + b1 * b1 + s0 * s0 + s1 * s1;

    float loss = obj + (present ? (cls + 5.0f * box) : 0.0f);

    // ---- reduce: wave-64 shuffle, then 2 wave partials, then 1 atomic ----
    #pragma unroll
    for (int off = 32; off > 0; off >>= 1)
        loss += __shfl_down(loss, off);

    __shared__ float warp_sums[TPB / 64];
    int wid  = tid >> 6;
    int lane = tid & 63;
    if (lane == 0) warp_sums[wid] = loss;
    __syncthreads();

    if (tid == 0) {
        float s = warp_sums[0] + warp_sums[1];
        atomicAdd(out, s);
    }
}

extern "C" void kernel_launch(void* const* d_in, const int* in_sizes, int n_in,
                              void* d_out, int out_size, void* d_ws, size_t ws_size,
                              hipStream_t stream)
{
    const float* pred = (const float*)d_in[0];
    const float* targ = (const float*)d_in[1];
    float* out = (float*)d_out;

    // harness poisons d_out with 0xAA before every launch -> zero it (capture-safe)
    hipMemsetAsync(out, 0, sizeof(float), stream);

    int ncells = in_sizes[0] / PRED_CH;      // 16384*49 = 802816, divisible by 128
    int blocks = ncells / TPB;               // 6272, exact
    hipLaunchKernelGGL(yolo_loss_kernel, dim3(blocks), dim3(TPB), 0, stream,
                       pred, targ, out);
}

// Round 3
// 197.914 us; speedup vs baseline: 1.2159x; 1.2159x over previous
//
#include <hip/hip_runtime.h>
#include <stdint.h>

// YOLO loss, B=16384, 7x7 grid, pred=30ch f32, targ=25ch f32 -> scalar sum.
// Round-2 diagnosis: latency-bound (115us @ 9.5% HBM, VALUBusy 6.6%) -- the
// per-element global->LDS scatter serialized ~14 load latencies per thread.
// Fix: global_load_lds width=16 (no VGPR round-trip, linear LDS dest),
// one vmcnt drain per tile, 5 blocks/CU hide each other's stalls.
// K=4 tiles per block -> 1568 blocks, 4x fewer atomics.

#define TPB    128
#define CELLS  128                 // cells per tile
#define NTILES 6272                // 802816 / 128
#define GRID   1568                // NTILES / KTILES
#define KTILES 4
#define P_F4   960                 // 128*30/4 float4 per pred tile
#define T_F4   800                 // 128*25/4 float4 per targ tile

// global_load_lds: dest must be linear (uniform base + lane*16) -- our
// layout is exactly that. Casting idiom per composable_kernel: LDS generic
// pointer's low 32 bits are the LDS byte offset (apertures 4GB-aligned).
#define GL2LDS(gptr, lptr)                                                    \
    __builtin_amdgcn_global_load_lds(                                         \
        (const __attribute__((address_space(1))) void*)(gptr),                \
        (__attribute__((address_space(3))) void*)(uintptr_t)(lptr), 16, 0, 0)

__global__ __launch_bounds__(TPB) void yolo_loss_kernel(
    const float* __restrict__ pred,
    const float* __restrict__ targ,
    float* __restrict__ out)
{
    __shared__ float4 sp4[P_F4];   // 15360 B, pred tile, linear
    __shared__ float4 st4[T_F4];   // 12800 B, targ tile, linear

    const int tid = threadIdx.x;
    const float* sp = (const float*)sp4;
    const float* st = (const float*)st4;

    float loss = 0.0f;
    int tile = blockIdx.x;

    for (int j = 0; j < KTILES; ++j) {
        // ---- stage tile: 17 global_load_lds dwordx4 per thread-group ----
        const float4* gp = (const float4*)pred + (size_t)tile * P_F4;
        const float4* gt = (const float4*)targ + (size_t)tile * T_F4;
        #pragma unroll
        for (int r = 0; r < 7; ++r) GL2LDS(gp + tid + r * TPB, sp4 + tid + r * TPB);
        if (tid < 64)               GL2LDS(gp + 896 + tid,     sp4 + 896 + tid);
        #pragma unroll
        for (int r = 0; r < 6; ++r) GL2LDS(gt + tid + r * TPB, st4 + tid + r * TPB);
        if (tid < 32)               GL2LDS(gt + 768 + tid,     st4 + 768 + tid);

        __syncthreads();   // drains vmcnt(0): all staging visible to block

        // ---- per-cell compute: thread tid owns cell tid ----
        // pred: float2 reads (base 30*tid floats is even -> 8B aligned)
        const float2* pv2 = (const float2*)(sp + tid * 30);
        float pv[30];
        #pragma unroll
        for (int i = 0; i < 15; ++i) {
            float2 v = pv2[i];
            pv[2*i] = v.x; pv[2*i+1] = v.y;
        }
        const float* tvp = st + tid * 25;
        float tv[25];
        #pragma unroll
        for (int i = 0; i < 25; ++i) tv[i] = tvp[i];

        float c1 = pv[4], c2 = pv[9], cc = tv[4];
        bool present = (cc == 1.0f);
        bool resp1   = (c1 > c2);

        float d1 = c1 - cc, d2 = c2 - cc;
        float obj_present = resp1 ? d1 * d1 : d2 * d2;
        float obj_absent  = 0.5f * (c1 * c1 + c2 * c2);
        float obj = present ? obj_present : obj_absent;

        float cls = 0.0f;
        #pragma unroll
        for (int k = 0; k < 20; ++k) {
            float d = pv[10 + k] - tv[5 + k];
            cls += d * d;
        }

        float pc0 = resp1 ? pv[0] : pv[5];
        float pc1 = resp1 ? pv[1] : pv[6];
        float ph0 = resp1 ? pv[2] : pv[7];
        float ph1 = resp1 ? pv[3] : pv[8];
        float b0 = pc0 - tv[0];
        float b1 = pc1 - tv[1];
        float s0 = sqrtf(ph0) - sqrtf(tv[2]);
        float s1 = sqrtf(ph1) - sqrtf(tv[3]);
        float box = b0 * b0 + b1 * b1 + s0 * s0 + s1 * s1;

        loss += obj + (present ? (cls + 5.0f * box) : 0.0f);

        __syncthreads();   // all waves done reading LDS before next overwrite
        tile += GRID;
    }

    // ---- block reduce: wave-64 shuffle -> 2 partials -> 1 atomic ----
    #pragma unroll
    for (int off = 32; off > 0; off >>= 1)
        loss += __shfl_down(loss, off);

    __shared__ float warp_sums[TPB / 64];
    if ((tid & 63) == 0) warp_sums[tid >> 6] = loss;
    __syncthreads();

    if (tid == 0)
        atomicAdd(out, warp_sums[0] + warp_sums[1]);
}

extern "C" void kernel_launch(void* const* d_in, const int* in_sizes, int n_in,
                              void* d_out, int out_size, void* d_ws, size_t ws_size,
                              hipStream_t stream)
{
    const float* pred = (const float*)d_in[0];
    const float* targ = (const float*)d_in[1];
    float* out = (float*)d_out;

    // harness poisons d_out with 0xAA before every launch -> zero it (capture-safe)
    hipMemsetAsync(out, 0, sizeof(float), stream);

    hipLaunchKernelGGL(yolo_loss_kernel, dim3(GRID), dim3(TPB), 0, stream,
                       pred, targ, out);
}